// Round 4
// baseline (98.826 us; speedup 1.0000x reference)
//
#include <hip/hip_runtime.h>

#define NN 100000
#define NE 3200000
#define NQ (NE / 4)

// ---- bucketed-scatter plan constants ----
#define NSLICE 64
#define WPB 16                       // waves per block (1024 threads)
#define NWAVE (NSLICE * WPB)         // 1024 global wave ids
#define EPW (NE / NWAVE)             // 3125 edges per wave (exact)
#define CHUNK 25000
#define NCHUNK 4

// --------------------------------------------------------------------------
// Bucket kernel: partition edges by dst-chunk into per-(chunk,wave) regions.
// No atomics: wave-uniform counters + ballot/popc for lane slots.
// Packed edge: dst_local (15b) << 17 | src (17b).
__global__ __launch_bounds__(1024) void bucket_kernel(
        const int* __restrict__ src, const int* __restrict__ dst,
        unsigned* __restrict__ bkt, int* __restrict__ counts) {
    const int lane = threadIdx.x & 63;
    const int w = threadIdx.x >> 6;
    const int wg = blockIdx.x * WPB + w;
    const long long e0 = (long long)wg * EPW;
    const unsigned long long lt = (1ULL << lane) - 1ULL;
    int c0 = 0, c1 = 0, c2 = 0, c3 = 0;
    unsigned* b0 = bkt + (size_t)(0 * NWAVE + wg) * EPW;
    unsigned* b1 = bkt + (size_t)(1 * NWAVE + wg) * EPW;
    unsigned* b2 = bkt + (size_t)(2 * NWAVE + wg) * EPW;
    unsigned* b3 = bkt + (size_t)(3 * NWAVE + wg) * EPW;
    const int iters = (EPW + 63) / 64;
    for (int k = 0; k < iters; ++k) {
        const int off = k * 64 + lane;
        const bool valid = off < EPW;
        int d = 0, sv = 0;
        if (valid) { d = dst[e0 + off]; sv = src[e0 + off]; }
        const int myc = d / CHUNK;                       // magic-mul div
        const unsigned pk = ((unsigned)(d - myc * CHUNK) << 17) | (unsigned)sv;
        unsigned long long m;
        m = __ballot(valid && myc == 0);
        if (valid && myc == 0) b0[c0 + (int)__popcll(m & lt)] = pk;
        c0 += (int)__popcll(m);
        m = __ballot(valid && myc == 1);
        if (valid && myc == 1) b1[c1 + (int)__popcll(m & lt)] = pk;
        c1 += (int)__popcll(m);
        m = __ballot(valid && myc == 2);
        if (valid && myc == 2) b2[c2 + (int)__popcll(m & lt)] = pk;
        c2 += (int)__popcll(m);
        m = __ballot(valid && myc == 3);
        if (valid && myc == 3) b3[c3 + (int)__popcll(m & lt)] = pk;
        c3 += (int)__popcll(m);
    }
    if (lane == 0) {
        counts[0 * NWAVE + wg] = c0;
        counts[1 * NWAVE + wg] = c1;
        counts[2 * NWAVE + wg] = c2;
        counts[3 * NWAVE + wg] = c3;
    }
}

// Scatter: block (s,c) accumulates its 16 sub-buckets into a 100 KB LDS
// chunk accumulator, then writes one dense partial. Every edge useful.
__global__ __launch_bounds__(1024) void scatter_bkt_kernel(
        const float* __restrict__ h,
        const unsigned* __restrict__ bkt, const int* __restrict__ counts,
        float* __restrict__ partial) {
    __shared__ float acc[CHUNK];
    const int s = blockIdx.x, c = blockIdx.y;
    for (int i = threadIdx.x; i < CHUNK; i += 1024) acc[i] = 0.0f;
    __syncthreads();
    const int lane = threadIdx.x & 63;
    const int w = threadIdx.x >> 6;
    const int wg = s * WPB + w;
    const int n = counts[c * NWAVE + wg];
    const unsigned* b = bkt + (size_t)(c * NWAVE + wg) * EPW;
    for (int k = lane; k < n; k += 64) {
        const unsigned e = b[k];
        atomicAdd(&acc[e >> 17], h[e & 0x1FFFF]);
    }
    __syncthreads();
    float* out = partial + ((size_t)c * NSLICE + s) * CHUNK;
    for (int i = threadIdx.x; i < CHUNK; i += 1024) out[i] = acc[i];
}

// agg1 = sum over slice partials; s = sum_j relu(agg1*W1+b1)*W2
__global__ __launch_bounds__(256) void reduce_mlp_kernel(
        const float* __restrict__ partial,
        const float* __restrict__ W1, const float* __restrict__ b1,
        const float* __restrict__ W2,
        float* __restrict__ sout, int n) {
    int i = blockIdx.x * blockDim.x + threadIdx.x;
    if (i >= n) return;
    const int c = i / CHUNK;
    const int idx = i - c * CHUNK;
    const float* base = partial + (size_t)c * NSLICE * CHUNK + idx;
    float a = 0.0f;
#pragma unroll 8
    for (int s = 0; s < NSLICE; ++s) a += base[(size_t)s * CHUNK];
    float r = 0.0f;
#pragma unroll
    for (int j = 0; j < 16; ++j)
        r = fmaf(fmaxf(fmaf(a, W1[j], b1[j]), 0.0f), W2[j], r);
    sout[i] = r;
}

__global__ __launch_bounds__(256) void reduce_final_kernel(
        const float* __restrict__ partial,
        const float* __restrict__ b2,
        float* __restrict__ out, int n) {
    int i = blockIdx.x * blockDim.x + threadIdx.x;
    if (i >= n) return;
    const int c = i / CHUNK;
    const int idx = i - c * CHUNK;
    const float* base = partial + (size_t)c * NSLICE * CHUNK + idx;
    float a = 0.0f;
#pragma unroll 8
    for (int s = 0; s < NSLICE; ++s) a += base[(size_t)s * CHUNK];
    out[i] = fmaxf(a + b2[0], 0.0f);
}

// ---------------- Fallback A: R3 chunked-LDS conditional-scan path ----------
template <int CB>
__global__ __launch_bounds__(1024) void scatter_lds_kernel(
        const float* __restrict__ h,
        const int4* __restrict__ src4,
        const int4* __restrict__ dst4,
        float* __restrict__ partial, int nslices) {
    __shared__ float acc[1 << CB];
    const int cmask = (1 << CB) - 1;
    const int s = blockIdx.x, c = blockIdx.y;
    for (int i = threadIdx.x; i < (1 << CB); i += blockDim.x) acc[i] = 0.0f;
    __syncthreads();
    const int q0 = (int)(((long long)NQ * s) / nslices);
    const int q1 = (int)(((long long)NQ * (s + 1)) / nslices);
    for (int q = q0 + threadIdx.x; q < q1; q += blockDim.x) {
        int4 d = dst4[q];
        int4 sv = src4[q];
        if ((d.x >> CB) == c) atomicAdd(&acc[d.x & cmask], h[sv.x]);
        if ((d.y >> CB) == c) atomicAdd(&acc[d.y & cmask], h[sv.y]);
        if ((d.z >> CB) == c) atomicAdd(&acc[d.z & cmask], h[sv.z]);
        if ((d.w >> CB) == c) atomicAdd(&acc[d.w & cmask], h[sv.w]);
    }
    __syncthreads();
    float* out = partial + (((size_t)c * nslices + s) << CB);
    for (int i = threadIdx.x; i < (1 << CB); i += blockDim.x) out[i] = acc[i];
}
template <int CB>
__global__ __launch_bounds__(256) void reduce_mlp_p2_kernel(
        const float* __restrict__ partial, int nslices,
        const float* __restrict__ W1, const float* __restrict__ b1,
        const float* __restrict__ W2,
        float* __restrict__ sout, int n) {
    int i = blockIdx.x * blockDim.x + threadIdx.x;
    if (i >= n) return;
    const int c = i >> CB, idx = i & ((1 << CB) - 1);
    const float* base = partial + (((size_t)c * nslices) << CB) + idx;
    float a = 0.0f;
#pragma unroll 8
    for (int s = 0; s < nslices; ++s) a += base[(size_t)s << CB];
    float r = 0.0f;
#pragma unroll
    for (int j = 0; j < 16; ++j)
        r = fmaf(fmaxf(fmaf(a, W1[j], b1[j]), 0.0f), W2[j], r);
    sout[i] = r;
}
template <int CB>
__global__ __launch_bounds__(256) void reduce_final_p2_kernel(
        const float* __restrict__ partial, int nslices,
        const float* __restrict__ b2,
        float* __restrict__ out, int n) {
    int i = blockIdx.x * blockDim.x + threadIdx.x;
    if (i >= n) return;
    const int c = i >> CB, idx = i & ((1 << CB) - 1);
    const float* base = partial + (((size_t)c * nslices) << CB) + idx;
    float a = 0.0f;
#pragma unroll 8
    for (int s = 0; s < nslices; ++s) a += base[(size_t)s << CB];
    out[i] = fmaxf(a + b2[0], 0.0f);
}

// ---------------- Fallback B: global-atomic path ----------------------------
__global__ void zero_kernel(float* __restrict__ p, int n) {
    int i = blockIdx.x * blockDim.x + threadIdx.x;
    int st = gridDim.x * blockDim.x;
    for (; i < n; i += st) p[i] = 0.0f;
}
__global__ __launch_bounds__(256) void edge_scatter_kernel(
        const float* __restrict__ h, const int4* __restrict__ src4,
        const int4* __restrict__ dst4, float* __restrict__ agg, int nquad) {
    int i = blockIdx.x * blockDim.x + threadIdx.x;
    if (i >= nquad) return;
    int4 s = src4[i]; int4 d = dst4[i];
    atomicAdd(&agg[d.x], h[s.x]);
    atomicAdd(&agg[d.y], h[s.y]);
    atomicAdd(&agg[d.z], h[s.z]);
    atomicAdd(&agg[d.w], h[s.w]);
}
__global__ __launch_bounds__(256) void mlp_kernel(
        const float* __restrict__ agg1, const float* __restrict__ W1,
        const float* __restrict__ b1, const float* __restrict__ W2,
        float* __restrict__ sout, int n) {
    int i = blockIdx.x * blockDim.x + threadIdx.x;
    if (i >= n) return;
    float a = agg1[i], r = 0.0f;
#pragma unroll
    for (int j = 0; j < 16; ++j)
        r = fmaf(fmaxf(fmaf(a, W1[j], b1[j]), 0.0f), W2[j], r);
    sout[i] = r;
}
__global__ __launch_bounds__(256) void finalize_kernel(
        float* __restrict__ out, const float* __restrict__ b2, int n) {
    int i = blockIdx.x * blockDim.x + threadIdx.x;
    if (i >= n) return;
    out[i] = fmaxf(out[i] + b2[0], 0.0f);
}

extern "C" void kernel_launch(void* const* d_in, const int* in_sizes, int n_in,
                              void* d_out, int out_size, void* d_ws, size_t ws_size,
                              hipStream_t stream) {
    const float* features = (const float*)d_in[0];
    const int*   src      = (const int*)d_in[1];
    const int*   dst      = (const int*)d_in[2];
    const float* W1       = (const float*)d_in[3];
    const float* b1       = (const float*)d_in[4];
    const float* W2       = (const float*)d_in[5];
    const float* b2       = (const float*)d_in[6];
    float* out = (float*)d_out;

    const int nb = (NN + 255) / 256;

    // Plan A: bucketed scatter (needs ~77.3 MB ws)
    {
        const size_t bkt_elems  = (size_t)NCHUNK * NWAVE * EPW;      // 12.8M u32
        const size_t cnt_elems  = (size_t)NCHUNK * NWAVE;            // 4096 int
        const size_t part_elems = (size_t)NCHUNK * NSLICE * CHUNK;   // 6.4M f32
        const size_t need = (bkt_elems + cnt_elems + part_elems + NN) * 4;
        if (ws_size >= need) {
            unsigned* bkt  = (unsigned*)d_ws;
            int* counts    = (int*)(bkt + bkt_elems);
            float* partial = (float*)(counts + cnt_elems);
            float* sbuf    = partial + part_elems;

            bucket_kernel<<<NSLICE, 1024, 0, stream>>>(src, dst, bkt, counts);
            dim3 g(NSLICE, NCHUNK);
            scatter_bkt_kernel<<<g, 1024, 0, stream>>>(features, bkt, counts, partial);
            reduce_mlp_kernel<<<nb, 256, 0, stream>>>(partial, W1, b1, W2, sbuf, NN);
            scatter_bkt_kernel<<<g, 1024, 0, stream>>>(sbuf, bkt, counts, partial);
            reduce_final_kernel<<<nb, 256, 0, stream>>>(partial, b2, out, NN);
            return;
        }
    }
    // Fallback A: R3 conditional-scan path (~34 MB ws)
    {
        const int S = 64, C = 4;
        const size_t psz = ((size_t)C * S) << 15;
        const size_t need = (psz + NN) * sizeof(float);
        const int4* src4 = (const int4*)src;
        const int4* dst4 = (const int4*)dst;
        if (ws_size >= need) {
            float* partial = (float*)d_ws;
            float* sbuf = partial + psz;
            dim3 g(S, C);
            scatter_lds_kernel<15><<<g, 1024, 0, stream>>>(features, src4, dst4, partial, S);
            reduce_mlp_p2_kernel<15><<<nb, 256, 0, stream>>>(partial, S, W1, b1, W2, sbuf, NN);
            scatter_lds_kernel<15><<<g, 1024, 0, stream>>>(sbuf, src4, dst4, partial, S);
            reduce_final_p2_kernel<15><<<nb, 256, 0, stream>>>(partial, S, b2, out, NN);
            return;
        }
    }
    // Fallback B: global atomics
    {
        float* agg1 = (float*)d_ws;
        float* sbuf = agg1 + NN;
        const int4* src4 = (const int4*)src;
        const int4* dst4 = (const int4*)dst;
        const int eb = (NQ + 255) / 256;
        zero_kernel<<<256, 256, 0, stream>>>(agg1, NN);
        edge_scatter_kernel<<<eb, 256, 0, stream>>>(features, src4, dst4, agg1, NQ);
        mlp_kernel<<<nb, 256, 0, stream>>>(agg1, W1, b1, W2, sbuf, NN);
        zero_kernel<<<256, 256, 0, stream>>>(out, NN);
        edge_scatter_kernel<<<eb, 256, 0, stream>>>(sbuf, src4, dst4, out, NQ);
        finalize_kernel<<<nb, 256, 0, stream>>>(out, b2, NN);
    }
}

// Round 5
// 75.526 us; speedup vs baseline: 1.3085x; 1.3085x over previous
//
#include <hip/hip_runtime.h>

#define NN 100000
#define NE 3200000
#define NQ (NE / 4)

// ---- bucketed-scatter plan constants ----
#define NTILE 12500                 // 256-edge tiles (NE/256, exact)
#define NWAVE 4096                  // bucket-writer waves
#define BCAP 1024                   // max edges per (chunk,wave) bucket: 4 tiles * 256
#define CHUNK 25000
#define NCHUNK 4
#define NSLICE 64                   // scatter slices (4096/64 = 64 sub-buckets each)
#define SUBS_PER_SLICE (NWAVE / NSLICE)

// --------------------------------------------------------------------------
// Bucket kernel: partition edges by dst-chunk into per-(chunk,wave) regions.
// 1024 blocks x 256 thr = 4096 waves; int4 edge loads; ballot compaction.
// Packed edge: dst_local (15b) << 17 | src (17b).
__global__ __launch_bounds__(256) void bucket_kernel(
        const int4* __restrict__ src4, const int4* __restrict__ dst4,
        unsigned* __restrict__ bkt, int* __restrict__ counts) {
    const int lane = threadIdx.x & 63;
    const int w = threadIdx.x >> 6;
    const int wg = blockIdx.x * 4 + w;
    const int t0 = (int)(((long long)wg * NTILE) / NWAVE);
    const int t1 = (int)(((long long)(wg + 1) * NTILE) / NWAVE);
    const unsigned long long lt = (1ULL << lane) - 1ULL;
    int cnt0 = 0, cnt1 = 0, cnt2 = 0, cnt3 = 0;
    unsigned* bp0 = bkt + (size_t)(0 * NWAVE + wg) * BCAP;
    unsigned* bp1 = bkt + (size_t)(1 * NWAVE + wg) * BCAP;
    unsigned* bp2 = bkt + (size_t)(2 * NWAVE + wg) * BCAP;
    unsigned* bp3 = bkt + (size_t)(3 * NWAVE + wg) * BCAP;
    for (int t = t0; t < t1; ++t) {
        const int4 d = dst4[t * 64 + lane];
        const int4 s = src4[t * 64 + lane];
        const int dd[4] = {d.x, d.y, d.z, d.w};
        const int ss[4] = {s.x, s.y, s.z, s.w};
#pragma unroll
        for (int j = 0; j < 4; ++j) {
            const int c = dd[j] / CHUNK;   // magic-mul div (constant)
            const unsigned pk =
                ((unsigned)(dd[j] - c * CHUNK) << 17) | (unsigned)ss[j];
            unsigned long long m;
            m = __ballot(c == 0);
            if (c == 0) bp0[cnt0 + (int)__popcll(m & lt)] = pk;
            cnt0 += (int)__popcll(m);
            m = __ballot(c == 1);
            if (c == 1) bp1[cnt1 + (int)__popcll(m & lt)] = pk;
            cnt1 += (int)__popcll(m);
            m = __ballot(c == 2);
            if (c == 2) bp2[cnt2 + (int)__popcll(m & lt)] = pk;
            cnt2 += (int)__popcll(m);
            m = __ballot(c == 3);
            if (c == 3) bp3[cnt3 + (int)__popcll(m & lt)] = pk;
            cnt3 += (int)__popcll(m);
        }
    }
    if (lane == 0) {
        counts[0 * NWAVE + wg] = cnt0;
        counts[1 * NWAVE + wg] = cnt1;
        counts[2 * NWAVE + wg] = cnt2;
        counts[3 * NWAVE + wg] = cnt3;
    }
}

// Scatter: block (s,c) drains 64 sub-buckets into a 100 KB LDS chunk
// accumulator (uint4 bucket reads -> 4 independent gathers/iter), then
// writes one dense partial. Every edge useful, no global atomics.
__global__ __launch_bounds__(1024) void scatter_bkt_kernel(
        const float* __restrict__ h,
        const unsigned* __restrict__ bkt, const int* __restrict__ counts,
        float* __restrict__ partial) {
    __shared__ float acc[CHUNK];
    const int s = blockIdx.x, c = blockIdx.y;
    float4* accv = (float4*)acc;
    for (int i = threadIdx.x; i < CHUNK / 4; i += 1024)
        accv[i] = make_float4(0.f, 0.f, 0.f, 0.f);
    __syncthreads();
    const int lane = threadIdx.x & 63;
    const int w = threadIdx.x >> 6;
#pragma unroll
    for (int k = 0; k < SUBS_PER_SLICE / 16; ++k) {
        const int wg = s * SUBS_PER_SLICE + w + k * 16;
        const int n = counts[c * NWAVE + wg];
        const unsigned* b = bkt + (size_t)(c * NWAVE + wg) * BCAP;
        const uint4* b4 = (const uint4*)b;
        const int n4 = n >> 2;
        for (int q = lane; q < n4; q += 64) {
            const uint4 e = b4[q];
            atomicAdd(&acc[e.x >> 17], h[e.x & 0x1FFFF]);
            atomicAdd(&acc[e.y >> 17], h[e.y & 0x1FFFF]);
            atomicAdd(&acc[e.z >> 17], h[e.z & 0x1FFFF]);
            atomicAdd(&acc[e.w >> 17], h[e.w & 0x1FFFF]);
        }
        const int base = n4 << 2;
        if (base + lane < n) {
            const unsigned e = b[base + lane];
            atomicAdd(&acc[e >> 17], h[e & 0x1FFFF]);
        }
    }
    __syncthreads();
    float4* out = (float4*)(partial + ((size_t)c * NSLICE + s) * CHUNK);
    for (int i = threadIdx.x; i < CHUNK / 4; i += 1024) out[i] = accv[i];
}

// agg1 = sum over slice partials; s = sum_j relu(agg1*W1+b1)*W2
__global__ __launch_bounds__(256) void reduce_mlp_kernel(
        const float* __restrict__ partial,
        const float* __restrict__ W1, const float* __restrict__ b1,
        const float* __restrict__ W2,
        float* __restrict__ sout, int n) {
    int i = blockIdx.x * blockDim.x + threadIdx.x;
    if (i >= n) return;
    const int c = i / CHUNK;
    const int idx = i - c * CHUNK;
    const float* base = partial + (size_t)c * NSLICE * CHUNK + idx;
    float a = 0.0f;
#pragma unroll 8
    for (int s = 0; s < NSLICE; ++s) a += base[(size_t)s * CHUNK];
    float r = 0.0f;
#pragma unroll
    for (int j = 0; j < 16; ++j)
        r = fmaf(fmaxf(fmaf(a, W1[j], b1[j]), 0.0f), W2[j], r);
    sout[i] = r;
}

__global__ __launch_bounds__(256) void reduce_final_kernel(
        const float* __restrict__ partial,
        const float* __restrict__ b2,
        float* __restrict__ out, int n) {
    int i = blockIdx.x * blockDim.x + threadIdx.x;
    if (i >= n) return;
    const int c = i / CHUNK;
    const int idx = i - c * CHUNK;
    const float* base = partial + (size_t)c * NSLICE * CHUNK + idx;
    float a = 0.0f;
#pragma unroll 8
    for (int s = 0; s < NSLICE; ++s) a += base[(size_t)s * CHUNK];
    out[i] = fmaxf(a + b2[0], 0.0f);
}

// ---------------- Fallback A: R3 chunked-LDS conditional-scan path ----------
template <int CB>
__global__ __launch_bounds__(1024) void scatter_lds_kernel(
        const float* __restrict__ h,
        const int4* __restrict__ src4,
        const int4* __restrict__ dst4,
        float* __restrict__ partial, int nslices) {
    __shared__ float acc[1 << CB];
    const int cmask = (1 << CB) - 1;
    const int s = blockIdx.x, c = blockIdx.y;
    for (int i = threadIdx.x; i < (1 << CB); i += blockDim.x) acc[i] = 0.0f;
    __syncthreads();
    const int q0 = (int)(((long long)NQ * s) / nslices);
    const int q1 = (int)(((long long)NQ * (s + 1)) / nslices);
    for (int q = q0 + threadIdx.x; q < q1; q += blockDim.x) {
        int4 d = dst4[q];
        int4 sv = src4[q];
        if ((d.x >> CB) == c) atomicAdd(&acc[d.x & cmask], h[sv.x]);
        if ((d.y >> CB) == c) atomicAdd(&acc[d.y & cmask], h[sv.y]);
        if ((d.z >> CB) == c) atomicAdd(&acc[d.z & cmask], h[sv.z]);
        if ((d.w >> CB) == c) atomicAdd(&acc[d.w & cmask], h[sv.w]);
    }
    __syncthreads();
    float* out = partial + (((size_t)c * nslices + s) << CB);
    for (int i = threadIdx.x; i < (1 << CB); i += blockDim.x) out[i] = acc[i];
}
template <int CB>
__global__ __launch_bounds__(256) void reduce_mlp_p2_kernel(
        const float* __restrict__ partial, int nslices,
        const float* __restrict__ W1, const float* __restrict__ b1,
        const float* __restrict__ W2,
        float* __restrict__ sout, int n) {
    int i = blockIdx.x * blockDim.x + threadIdx.x;
    if (i >= n) return;
    const int c = i >> CB, idx = i & ((1 << CB) - 1);
    const float* base = partial + (((size_t)c * nslices) << CB) + idx;
    float a = 0.0f;
#pragma unroll 8
    for (int s = 0; s < nslices; ++s) a += base[(size_t)s << CB];
    float r = 0.0f;
#pragma unroll
    for (int j = 0; j < 16; ++j)
        r = fmaf(fmaxf(fmaf(a, W1[j], b1[j]), 0.0f), W2[j], r);
    sout[i] = r;
}
template <int CB>
__global__ __launch_bounds__(256) void reduce_final_p2_kernel(
        const float* __restrict__ partial, int nslices,
        const float* __restrict__ b2,
        float* __restrict__ out, int n) {
    int i = blockIdx.x * blockDim.x + threadIdx.x;
    if (i >= n) return;
    const int c = i >> CB, idx = i & ((1 << CB) - 1);
    const float* base = partial + (((size_t)c * nslices) << CB) + idx;
    float a = 0.0f;
#pragma unroll 8
    for (int s = 0; s < nslices; ++s) a += base[(size_t)s << CB];
    out[i] = fmaxf(a + b2[0], 0.0f);
}

// ---------------- Fallback B: global-atomic path ----------------------------
__global__ void zero_kernel(float* __restrict__ p, int n) {
    int i = blockIdx.x * blockDim.x + threadIdx.x;
    int st = gridDim.x * blockDim.x;
    for (; i < n; i += st) p[i] = 0.0f;
}
__global__ __launch_bounds__(256) void edge_scatter_kernel(
        const float* __restrict__ h, const int4* __restrict__ src4,
        const int4* __restrict__ dst4, float* __restrict__ agg, int nquad) {
    int i = blockIdx.x * blockDim.x + threadIdx.x;
    if (i >= nquad) return;
    int4 s = src4[i]; int4 d = dst4[i];
    atomicAdd(&agg[d.x], h[s.x]);
    atomicAdd(&agg[d.y], h[s.y]);
    atomicAdd(&agg[d.z], h[s.z]);
    atomicAdd(&agg[d.w], h[s.w]);
}
__global__ __launch_bounds__(256) void mlp_kernel(
        const float* __restrict__ agg1, const float* __restrict__ W1,
        const float* __restrict__ b1, const float* __restrict__ W2,
        float* __restrict__ sout, int n) {
    int i = blockIdx.x * blockDim.x + threadIdx.x;
    if (i >= n) return;
    float a = agg1[i], r = 0.0f;
#pragma unroll
    for (int j = 0; j < 16; ++j)
        r = fmaf(fmaxf(fmaf(a, W1[j], b1[j]), 0.0f), W2[j], r);
    sout[i] = r;
}
__global__ __launch_bounds__(256) void finalize_kernel(
        float* __restrict__ out, const float* __restrict__ b2, int n) {
    int i = blockIdx.x * blockDim.x + threadIdx.x;
    if (i >= n) return;
    out[i] = fmaxf(out[i] + b2[0], 0.0f);
}

extern "C" void kernel_launch(void* const* d_in, const int* in_sizes, int n_in,
                              void* d_out, int out_size, void* d_ws, size_t ws_size,
                              hipStream_t stream) {
    const float* features = (const float*)d_in[0];
    const int*   src      = (const int*)d_in[1];
    const int*   dst      = (const int*)d_in[2];
    const float* W1       = (const float*)d_in[3];
    const float* b1       = (const float*)d_in[4];
    const float* W2       = (const float*)d_in[5];
    const float* b2       = (const float*)d_in[6];
    float* out = (float*)d_out;

    const int nb = (NN + 255) / 256;

    // Plan A: bucketed scatter (needs ~94 MB ws)
    {
        const size_t bkt_elems  = (size_t)NCHUNK * NWAVE * BCAP;     // 16.8M u32
        const size_t cnt_elems  = (size_t)NCHUNK * NWAVE;            // 16384 int
        const size_t part_elems = (size_t)NCHUNK * NSLICE * CHUNK;   // 6.4M f32
        const size_t need = (bkt_elems + cnt_elems + part_elems + NN) * 4;
        if (ws_size >= need) {
            unsigned* bkt  = (unsigned*)d_ws;
            int* counts    = (int*)(bkt + bkt_elems);
            float* partial = (float*)(counts + cnt_elems);
            float* sbuf    = partial + part_elems;

            bucket_kernel<<<NWAVE / 4, 256, 0, stream>>>(
                (const int4*)src, (const int4*)dst, bkt, counts);
            dim3 g(NSLICE, NCHUNK);
            scatter_bkt_kernel<<<g, 1024, 0, stream>>>(features, bkt, counts, partial);
            reduce_mlp_kernel<<<nb, 256, 0, stream>>>(partial, W1, b1, W2, sbuf, NN);
            scatter_bkt_kernel<<<g, 1024, 0, stream>>>(sbuf, bkt, counts, partial);
            reduce_final_kernel<<<nb, 256, 0, stream>>>(partial, b2, out, NN);
            return;
        }
    }
    // Fallback A: R3 conditional-scan path (~34 MB ws)
    {
        const int S = 64, C = 4;
        const size_t psz = ((size_t)C * S) << 15;
        const size_t need = (psz + NN) * sizeof(float);
        const int4* src4 = (const int4*)src;
        const int4* dst4 = (const int4*)dst;
        if (ws_size >= need) {
            float* partial = (float*)d_ws;
            float* sbuf = partial + psz;
            dim3 g(S, C);
            scatter_lds_kernel<15><<<g, 1024, 0, stream>>>(features, src4, dst4, partial, S);
            reduce_mlp_p2_kernel<15><<<nb, 256, 0, stream>>>(partial, S, W1, b1, W2, sbuf, NN);
            scatter_lds_kernel<15><<<g, 1024, 0, stream>>>(sbuf, src4, dst4, partial, S);
            reduce_final_p2_kernel<15><<<nb, 256, 0, stream>>>(partial, S, b2, out, NN);
            return;
        }
    }
    // Fallback B: global atomics
    {
        float* agg1 = (float*)d_ws;
        float* sbuf = agg1 + NN;
        const int4* src4 = (const int4*)src;
        const int4* dst4 = (const int4*)dst;
        const int eb = (NQ + 255) / 256;
        zero_kernel<<<256, 256, 0, stream>>>(agg1, NN);
        edge_scatter_kernel<<<eb, 256, 0, stream>>>(features, src4, dst4, agg1, NQ);
        mlp_kernel<<<nb, 256, 0, stream>>>(agg1, W1, b1, W2, sbuf, NN);
        zero_kernel<<<256, 256, 0, stream>>>(out, NN);
        edge_scatter_kernel<<<eb, 256, 0, stream>>>(sbuf, src4, dst4, out, NQ);
        finalize_kernel<<<nb, 256, 0, stream>>>(out, b2, NN);
    }
}

// Round 6
// 64.589 us; speedup vs baseline: 1.5301x; 1.1693x over previous
//
#include <hip/hip_runtime.h>

#define NN 100000
#define NE 3200000
#define NQ (NE / 4)            // 800000 int4 quads

// ---- bucketed-scatter plan constants ----
#define NCHUNK 32
#define CHUNK 3125             // 32 * 3125 = 100000 exactly; 12.5 KB LDS
#define NBB 512                // bucket blocks
#define BCAP 320               // per-(chunk,block) capacity: mean 195 + 9 sigma
#define NSLICE 16              // scatter slices
#define GPS (NBB / NSLICE)     // bucket-block groups per slice = 32

// --------------------------------------------------------------------------
// Bucket: partition edges by dst-chunk into per-(chunk,block) segments.
// Slot assignment via LDS atomic counters (1 LDS RMW per edge, no ballots).
// Packed entry: dst_local (12b) << 17 | src (17b).
__global__ __launch_bounds__(1024) void bucket_kernel(
        const int4* __restrict__ src4, const int4* __restrict__ dst4,
        unsigned* __restrict__ bkt, int* __restrict__ counts) {
    __shared__ int cnt[NCHUNK];
    if (threadIdx.x < NCHUNK) cnt[threadIdx.x] = 0;
    __syncthreads();
    const int b = blockIdx.x;
    const int q0 = (int)(((long long)b * NQ) / NBB);
    const int q1 = (int)(((long long)(b + 1) * NQ) / NBB);
    for (int q = q0 + threadIdx.x; q < q1; q += 1024) {
        const int4 d = dst4[q];
        const int4 s = src4[q];
        const int dd[4] = {d.x, d.y, d.z, d.w};
        const int ss[4] = {s.x, s.y, s.z, s.w};
#pragma unroll
        for (int j = 0; j < 4; ++j) {
            const int c = dd[j] / CHUNK;                  // magic-mul div
            const int slot = atomicAdd(&cnt[c], 1);
            bkt[((size_t)c * NBB + b) * BCAP + slot] =
                ((unsigned)(dd[j] - c * CHUNK) << 17) | (unsigned)ss[j];
        }
    }
    __syncthreads();
    if (threadIdx.x < NCHUNK)
        counts[threadIdx.x * NBB + b] = cnt[threadIdx.x];
}

// Scatter: block (s,c) drains 32 segments (2 per wave) into a 12.5 KB LDS
// chunk accumulator, then writes one dense partial. 2 blocks/CU -> 8 w/SIMD.
__global__ __launch_bounds__(1024) void scatter_bkt_kernel(
        const float* __restrict__ h,
        const unsigned* __restrict__ bkt, const int* __restrict__ counts,
        float* __restrict__ partial) {
    __shared__ float acc[CHUNK];
    const int s = blockIdx.x, c = blockIdx.y;
    for (int i = threadIdx.x; i < CHUNK; i += 1024) acc[i] = 0.0f;
    __syncthreads();
    const int lane = threadIdx.x & 63;
    const int w = threadIdx.x >> 6;
#pragma unroll
    for (int k = 0; k < 2; ++k) {
        const int b = s * GPS + w + k * 16;
        const int n = counts[c * NBB + b];
        const unsigned* bp = bkt + ((size_t)c * NBB + b) * BCAP;
        const uint4* bp4 = (const uint4*)bp;
        const int n4 = n >> 2;
        for (int q = lane; q < n4; q += 64) {
            const uint4 e = bp4[q];
            atomicAdd(&acc[e.x >> 17], h[e.x & 0x1FFFF]);
            atomicAdd(&acc[e.y >> 17], h[e.y & 0x1FFFF]);
            atomicAdd(&acc[e.z >> 17], h[e.z & 0x1FFFF]);
            atomicAdd(&acc[e.w >> 17], h[e.w & 0x1FFFF]);
        }
        const int base = n4 << 2;
        if (base + lane < n) {
            const unsigned e = bp[base + lane];
            atomicAdd(&acc[e >> 17], h[e & 0x1FFFF]);
        }
    }
    __syncthreads();
    float* out = partial + ((size_t)c * NSLICE + s) * CHUNK;
    for (int i = threadIdx.x; i < CHUNK; i += 1024) out[i] = acc[i];
}

// agg1 = sum over 16 slice partials; s = sum_j relu(agg1*W1+b1)*W2
__global__ __launch_bounds__(256) void reduce_mlp_kernel(
        const float* __restrict__ partial,
        const float* __restrict__ W1, const float* __restrict__ b1,
        const float* __restrict__ W2,
        float* __restrict__ sout, int n) {
    int i = blockIdx.x * blockDim.x + threadIdx.x;
    if (i >= n) return;
    const int c = i / CHUNK;
    const int idx = i - c * CHUNK;
    const float* base = partial + (size_t)c * NSLICE * CHUNK + idx;
    float a = 0.0f;
#pragma unroll
    for (int s = 0; s < NSLICE; ++s) a += base[(size_t)s * CHUNK];
    float r = 0.0f;
#pragma unroll
    for (int j = 0; j < 16; ++j)
        r = fmaf(fmaxf(fmaf(a, W1[j], b1[j]), 0.0f), W2[j], r);
    sout[i] = r;
}

__global__ __launch_bounds__(256) void reduce_final_kernel(
        const float* __restrict__ partial,
        const float* __restrict__ b2,
        float* __restrict__ out, int n) {
    int i = blockIdx.x * blockDim.x + threadIdx.x;
    if (i >= n) return;
    const int c = i / CHUNK;
    const int idx = i - c * CHUNK;
    const float* base = partial + (size_t)c * NSLICE * CHUNK + idx;
    float a = 0.0f;
#pragma unroll
    for (int s = 0; s < NSLICE; ++s) a += base[(size_t)s * CHUNK];
    out[i] = fmaxf(a + b2[0], 0.0f);
}

// ---------------- Fallback: global-atomic path ------------------------------
__global__ void zero_kernel(float* __restrict__ p, int n) {
    int i = blockIdx.x * blockDim.x + threadIdx.x;
    int st = gridDim.x * blockDim.x;
    for (; i < n; i += st) p[i] = 0.0f;
}
__global__ __launch_bounds__(256) void edge_scatter_kernel(
        const float* __restrict__ h, const int4* __restrict__ src4,
        const int4* __restrict__ dst4, float* __restrict__ agg, int nquad) {
    int i = blockIdx.x * blockDim.x + threadIdx.x;
    if (i >= nquad) return;
    int4 s = src4[i]; int4 d = dst4[i];
    atomicAdd(&agg[d.x], h[s.x]);
    atomicAdd(&agg[d.y], h[s.y]);
    atomicAdd(&agg[d.z], h[s.z]);
    atomicAdd(&agg[d.w], h[s.w]);
}
__global__ __launch_bounds__(256) void mlp_kernel(
        const float* __restrict__ agg1, const float* __restrict__ W1,
        const float* __restrict__ b1, const float* __restrict__ W2,
        float* __restrict__ sout, int n) {
    int i = blockIdx.x * blockDim.x + threadIdx.x;
    if (i >= n) return;
    float a = agg1[i], r = 0.0f;
#pragma unroll
    for (int j = 0; j < 16; ++j)
        r = fmaf(fmaxf(fmaf(a, W1[j], b1[j]), 0.0f), W2[j], r);
    sout[i] = r;
}
__global__ __launch_bounds__(256) void finalize_kernel(
        float* __restrict__ out, const float* __restrict__ b2, int n) {
    int i = blockIdx.x * blockDim.x + threadIdx.x;
    if (i >= n) return;
    out[i] = fmaxf(out[i] + b2[0], 0.0f);
}

extern "C" void kernel_launch(void* const* d_in, const int* in_sizes, int n_in,
                              void* d_out, int out_size, void* d_ws, size_t ws_size,
                              hipStream_t stream) {
    const float* features = (const float*)d_in[0];
    const int*   src      = (const int*)d_in[1];
    const int*   dst      = (const int*)d_in[2];
    const float* W1       = (const float*)d_in[3];
    const float* b1       = (const float*)d_in[4];
    const float* W2       = (const float*)d_in[5];
    const float* b2       = (const float*)d_in[6];
    float* out = (float*)d_out;

    const int nb = (NN + 255) / 256;

    // Plan A: bucketed scatter (~28 MB ws)
    {
        const size_t bkt_elems  = (size_t)NCHUNK * NBB * BCAP;       // 5.24M u32
        const size_t cnt_elems  = (size_t)NCHUNK * NBB;              // 16384 int
        const size_t part_elems = (size_t)NCHUNK * NSLICE * CHUNK;   // 1.6M f32
        const size_t need = (bkt_elems + cnt_elems + part_elems + NN) * 4;
        if (ws_size >= need) {
            unsigned* bkt  = (unsigned*)d_ws;
            int* counts    = (int*)(bkt + bkt_elems);
            float* partial = (float*)(counts + cnt_elems);
            float* sbuf    = partial + part_elems;

            bucket_kernel<<<NBB, 1024, 0, stream>>>(
                (const int4*)src, (const int4*)dst, bkt, counts);
            dim3 g(NSLICE, NCHUNK);
            scatter_bkt_kernel<<<g, 1024, 0, stream>>>(features, bkt, counts, partial);
            reduce_mlp_kernel<<<nb, 256, 0, stream>>>(partial, W1, b1, W2, sbuf, NN);
            scatter_bkt_kernel<<<g, 1024, 0, stream>>>(sbuf, bkt, counts, partial);
            reduce_final_kernel<<<nb, 256, 0, stream>>>(partial, b2, out, NN);
            return;
        }
    }
    // Fallback: global atomics
    {
        float* agg1 = (float*)d_ws;
        float* sbuf = agg1 + NN;
        const int4* src4 = (const int4*)src;
        const int4* dst4 = (const int4*)dst;
        const int eb = (NQ + 255) / 256;
        zero_kernel<<<256, 256, 0, stream>>>(agg1, NN);
        edge_scatter_kernel<<<eb, 256, 0, stream>>>(features, src4, dst4, agg1, NQ);
        mlp_kernel<<<nb, 256, 0, stream>>>(agg1, W1, b1, W2, sbuf, NN);
        zero_kernel<<<256, 256, 0, stream>>>(out, NN);
        edge_scatter_kernel<<<eb, 256, 0, stream>>>(sbuf, src4, dst4, out, NQ);
        finalize_kernel<<<nb, 256, 0, stream>>>(out, b2, NN);
    }
}